// Round 7
// baseline (562.342 us; speedup 1.0000x reference)
//
#include <hip/hip_runtime.h>
#include <hip/hip_bf16.h>
#include <math.h>

constexpr int Bc = 2, Sc = 2048, Dc = 1024, Hc = 16, HDc = 64;
constexpr int D3 = 3 * Dc;

typedef __bf16 bf16x8 __attribute__((ext_vector_type(8)));
typedef float f32x4 __attribute__((ext_vector_type(4)));

__device__ __forceinline__ void gll16(const void* g, void* l) {
  __builtin_amdgcn_global_load_lds((const __attribute__((address_space(1))) unsigned int*)g,
                                   (__attribute__((address_space(3))) unsigned int*)l,
                                   16, 0, 0);
}

__device__ __forceinline__ unsigned short f2bf(float v) {
  __hip_bfloat16 h = __float2bfloat16(v);
  return *(unsigned short*)&h;
}
__device__ __forceinline__ float b2f(unsigned short u) {
  unsigned v = ((unsigned)u) << 16;
  return __uint_as_float(v);
}

// ---------------- fp32 -> bf16 elementwise (4 elems/thread) ----------------
__global__ __launch_bounds__(256) void f2b_kernel(const float* __restrict__ in,
                                                  unsigned short* __restrict__ out) {
  int i = blockIdx.x * 256 + threadIdx.x;
  float4 v = ((const float4*)in)[i];
  ushort4 o;
  o.x = f2bf(v.x); o.y = f2bf(v.y); o.z = f2bf(v.z); o.w = f2bf(v.w);
  ((ushort4*)out)[i] = o;
}

// ---------------- RMSNorm: one block per row of 1024, bf16 out ----------------
__global__ __launch_bounds__(256) void rmsnorm_bf16_kernel(const float* __restrict__ in,
                                                           unsigned short* __restrict__ out) {
  int row = blockIdx.x;
  const float4* x4 = (const float4*)(in + (size_t)row * Dc);
  float4 v = x4[threadIdx.x];
  float s = v.x * v.x + v.y * v.y + v.z * v.z + v.w * v.w;
#pragma unroll
  for (int off = 1; off < 64; off <<= 1) s += __shfl_xor(s, off);
  __shared__ float wsum[4];
  if ((threadIdx.x & 63) == 0) wsum[threadIdx.x >> 6] = s;
  __syncthreads();
  float tot = wsum[0] + wsum[1] + wsum[2] + wsum[3];
  float r = rsqrtf(tot * (1.0f / Dc) + 1.1920928955078125e-07f);
  ushort4 o;
  o.x = f2bf(v.x * r); o.y = f2bf(v.y * r); o.z = f2bf(v.z * r); o.w = f2bf(v.w * r);
  ((ushort4*)(out + (size_t)row * Dc))[threadIdx.x] = o;
}

// ---------------- Householder product Q (64x64), 1 block, 64 threads ----------------
__global__ __launch_bounds__(64) void hh_kernel(const float* __restrict__ vs,
                                                float* __restrict__ Qout) {
  __shared__ float Qm[64][65];
  __shared__ float vsh[64];
  int t = threadIdx.x;
  for (int i = 0; i < 64; ++i) Qm[i][t] = (i == t) ? 1.0f : 0.0f;
  for (int it = 0; it < 32; ++it) {
    __syncthreads();
    vsh[t] = vs[it * 64 + t];
    __syncthreads();
    float nv = 0.0f;
    for (int i = 0; i < 64; ++i) nv += vsh[i] * vsh[i];
    float c = 2.0f / (nv + 1e-8f);
    float wj = 0.0f;
    for (int i = 0; i < 64; ++i) wj += vsh[i] * Qm[i][t];
    for (int i = 0; i < 64; ++i) Qm[i][t] -= c * vsh[i] * wj;
  }
  __syncthreads();
  for (int i = 0; i < 64; ++i) Qout[i * 64 + t] = Qm[i][t];
}

// ---------------- weight fold: out[n][:] = (Q @ W_head)[r][:] ----------------
// q rows scaled by 0.125*log2(e) (folds attention scale + exp2-domain softmax).
__global__ __launch_bounds__(256) void wqk_kernel(const float* __restrict__ W,
                                                  const float* __restrict__ Qm,
                                                  unsigned short* __restrict__ out) {
  int n = blockIdx.x;  // 0..2047
  int r = n & 63;
  int base = n & ~63;
  int t = threadIdx.x;
  float a0 = 0, a1 = 0, a2 = 0, a3 = 0;
  const float4* Wp = (const float4*)(W + (size_t)base * 1024) + t;
#pragma unroll 8
  for (int e = 0; e < 64; ++e) {
    float q = Qm[r * 64 + e];
    float4 wv = Wp[(size_t)e * 256];
    a0 += q * wv.x; a1 += q * wv.y; a2 += q * wv.z; a3 += q * wv.w;
  }
  float sc = (n < 1024) ? 0.18033688f : 1.0f;  // 0.125 * log2(e)
  ushort4 o;
  o.x = f2bf(a0 * sc); o.y = f2bf(a1 * sc); o.z = f2bf(a2 * sc); o.w = f2bf(a3 * sc);
  ((ushort4*)(out + (size_t)n * 1024))[t] = o;
}

// ---------------- RoPE rotate + head-major relayout (cos/sin inline) ----------------
__global__ __launch_bounds__(256) void rope_kernel(const unsigned short* __restrict__ qkv,
                                                   const float* __restrict__ rope_pos,
                                                   const float* __restrict__ inv_freq,
                                                   unsigned short* __restrict__ qb,
                                                   unsigned short* __restrict__ kb) {
  int t = threadIdx.x;
  int gid = blockIdx.x * 64 + (t >> 2);
  int sub = t & 3;
  int h = gid & 15;
  int which = (gid >> 4) & 1;
  int tok = gid >> 5;
  int s = tok & (Sc - 1), b = tok >> 11;
  const unsigned short* src = qkv + (size_t)tok * D3 + which * Dc + h * 64 + sub * 8;
  uint4 lov = *(const uint4*)src;
  uint4 hiv = *(const uint4*)(src + 32);
  const unsigned short* lp = (const unsigned short*)&lov;
  const unsigned short* hp = (const unsigned short*)&hiv;
  unsigned short olo[8], ohi[8];
  float pos = rope_pos[s * 2 + (sub >> 1)];
  const float4* fq = (const float4*)(inv_freq + (sub & 1) * 8);
  float4 f0 = fq[0], f1 = fq[1];
  float fr[8] = {f0.x, f0.y, f0.z, f0.w, f1.x, f1.y, f1.z, f1.w};
#pragma unroll
  for (int i = 0; i < 8; ++i) {
    float emb = pos * fr[i];
    float cs = cosf(emb), sn = sinf(emb);
    float lo = b2f(lp[i]), hi = b2f(hp[i]);
    olo[i] = f2bf(lo * cs - hi * sn);
    ohi[i] = f2bf(hi * cs + lo * sn);
  }
  unsigned short* dst = (which ? kb : qb) + ((size_t)((b * Hc + h) * Sc + s)) * 64 + sub * 8;
  *(uint4*)dst = *(uint4*)olo;
  *(uint4*)(dst + 32) = *(uint4*)ohi;
}

// ---------------- V transpose-cast ----------------
__global__ __launch_bounds__(256) void vt_kernel(const unsigned short* __restrict__ qkv,
                                                 unsigned short* __restrict__ vtb) {
  __shared__ unsigned short tile[64 * 72];
  int st = blockIdx.x;
  int bh = blockIdx.y;
  int b = bh >> 4, h = bh & 15;
  int t = threadIdx.x;
  int srow = t >> 2, c16 = (t & 3) * 16;
  const unsigned short* src =
      qkv + (size_t)(b * Sc + st * 64 + srow) * D3 + 2 * Dc + h * 64 + c16;
  uint4 a0 = *(const uint4*)src;
  uint4 a1 = *(const uint4*)(src + 8);
  *(uint4*)(tile + srow * 72 + c16) = a0;
  *(uint4*)(tile + srow * 72 + c16 + 8) = a1;
  __syncthreads();
  int d = t >> 2, sch = (t & 3) * 16;
  unsigned short tmp[16];
#pragma unroll
  for (int i = 0; i < 16; ++i) tmp[i] = tile[(sch + i) * 72 + d];
  unsigned short* dst = vtb + ((size_t)(bh * 64 + d)) * Sc + st * 64 + sch;
  *(uint4*)dst = *(uint4*)tmp;
  *(uint4*)(dst + 8) = *(uint4*)(tmp + 8);
}

// ---------------- bf16 MFMA GEMM, 128x128 tile, XOR-swizzled LDS ----------------
// LDS slot (row, c) holds global chunk c ^ (row&3); frag read of chunk l4 -> l4 ^ (frow&3).
// MODE 1: C bf16 = silu(A.W^T) * (A.W2^T)   MODE 3: C bf16
template <int MODE>
__global__ __launch_bounds__(256, 2) void mgemm(const unsigned short* __restrict__ A,
                                                const unsigned short* __restrict__ W,
                                                const unsigned short* __restrict__ W2,
                                                void* __restrict__ Cout,
                                                int M, int N, int K) {
  __shared__ unsigned short As[4096];
  __shared__ unsigned short Bs[4096];
  __shared__ unsigned short B2s[(MODE == 1) ? 4096 : 8];
  const int t = threadIdx.x;
  const int lane = t & 63;
  const int wave = t >> 6;
  const int wr = wave >> 1, wc = wave & 1;
  const int m0 = blockIdx.y * 128, n0 = blockIdx.x * 128;
  f32x4 acc[4][4] = {};
  f32x4 acc2[4][4] = {};
  const int srow = t >> 2;
  const int scg = ((t & 3) ^ (srow & 3)) * 8;  // swizzled global chunk for this lane
  const unsigned short* Ag = A + (size_t)(m0 + srow) * K + scg;
  const unsigned short* Wg = W + (size_t)(n0 + srow) * K + scg;
  const unsigned short* W2g = (MODE == 1) ? (W2 + (size_t)(n0 + srow) * K + scg) : nullptr;
  const size_t rstep = (size_t)64 * K;
  const int frow = lane & 15;
  const int fsw = ((lane >> 4) ^ (frow & 3)) * 8;  // swizzled chunk for frag reads
  for (int k0 = 0; k0 < K; k0 += 32) {
    __syncthreads();
    gll16(Ag + k0, As + t * 8);
    gll16(Ag + k0 + rstep, As + 2048 + t * 8);
    gll16(Wg + k0, Bs + t * 8);
    gll16(Wg + k0 + rstep, Bs + 2048 + t * 8);
    if (MODE == 1) {
      gll16(W2g + k0, B2s + t * 8);
      gll16(W2g + k0 + rstep, B2s + 2048 + t * 8);
    }
    __syncthreads();
    bf16x8 af[4], bq[4];
#pragma unroll
    for (int i = 0; i < 4; ++i)
      af[i] = *(const bf16x8*)(As + (wr * 64 + i * 16 + frow) * 32 + fsw);
#pragma unroll
    for (int j = 0; j < 4; ++j)
      bq[j] = *(const bf16x8*)(Bs + (wc * 64 + j * 16 + frow) * 32 + fsw);
#pragma unroll
    for (int i = 0; i < 4; ++i)
#pragma unroll
      for (int j = 0; j < 4; ++j)
        acc[i][j] = __builtin_amdgcn_mfma_f32_16x16x32_bf16(af[i], bq[j], acc[i][j], 0, 0, 0);
    if (MODE == 1) {
#pragma unroll
      for (int j = 0; j < 4; ++j)
        bq[j] = *(const bf16x8*)(B2s + (wc * 64 + j * 16 + frow) * 32 + fsw);
#pragma unroll
      for (int i = 0; i < 4; ++i)
#pragma unroll
        for (int j = 0; j < 4; ++j)
          acc2[i][j] = __builtin_amdgcn_mfma_f32_16x16x32_bf16(af[i], bq[j], acc2[i][j], 0, 0, 0);
    }
  }
  const int crow = wr * 64 + (lane >> 4) * 4;
  const int ccol = wc * 64 + (lane & 15);
#pragma unroll
  for (int i = 0; i < 4; ++i) {
#pragma unroll
    for (int j = 0; j < 4; ++j) {
#pragma unroll
      for (int r = 0; r < 4; ++r) {
        int row = m0 + crow + i * 16 + r;
        int col = n0 + ccol + j * 16;
        float v = acc[i][j][r];
        size_t off = (size_t)row * N + col;
        if (MODE == 1) {
          float sv = v / (1.0f + expf(-v));
          ((unsigned short*)Cout)[off] = f2bf(sv * acc2[i][j][r]);
        } else {
          ((unsigned short*)Cout)[off] = f2bf(v);
        }
      }
    }
  }
}

// ---------------- bf16 MFMA GEMM, 64x128 tile, XOR-swizzled LDS ----------------
// MODE 2: C fp32 = A.W^T + R
// MODE 4: Cout fp32 and Cout2 bf16
// MODE 5: Cout fp32 = R + R2 * sigmoid(A.W^T + bias[col])
template <int MODE>
__global__ __launch_bounds__(256, 3) void mgemm64(const unsigned short* __restrict__ A,
                                                  const unsigned short* __restrict__ W,
                                                  const float* __restrict__ R,
                                                  const float* __restrict__ R2,
                                                  const float* __restrict__ bias,
                                                  void* __restrict__ Cout,
                                                  void* __restrict__ Cout2,
                                                  int M, int N, int K) {
  __shared__ unsigned short As[2048];
  __shared__ unsigned short Bs[4096];
  const int t = threadIdx.x;
  const int lane = t & 63;
  const int wave = t >> 6;
  const int wr = wave >> 1, wc = wave & 1;
  const int m0 = blockIdx.y * 64, n0 = blockIdx.x * 128;
  f32x4 acc[2][4] = {};
  const int srow = t >> 2;
  const int scg = ((t & 3) ^ (srow & 3)) * 8;
  const unsigned short* Ag = A + (size_t)(m0 + srow) * K + scg;
  const unsigned short* Wg = W + (size_t)(n0 + srow) * K + scg;
  const size_t rstep = (size_t)64 * K;
  const int frow = lane & 15;
  const int fsw = ((lane >> 4) ^ (frow & 3)) * 8;
  for (int k0 = 0; k0 < K; k0 += 32) {
    __syncthreads();
    gll16(Ag + k0, As + t * 8);
    gll16(Wg + k0, Bs + t * 8);
    gll16(Wg + k0 + rstep, Bs + 2048 + t * 8);
    __syncthreads();
    bf16x8 af[2], bq[4];
#pragma unroll
    for (int i = 0; i < 2; ++i)
      af[i] = *(const bf16x8*)(As + (wr * 32 + i * 16 + frow) * 32 + fsw);
#pragma unroll
    for (int j = 0; j < 4; ++j)
      bq[j] = *(const bf16x8*)(Bs + (wc * 64 + j * 16 + frow) * 32 + fsw);
#pragma unroll
    for (int i = 0; i < 2; ++i)
#pragma unroll
      for (int j = 0; j < 4; ++j)
        acc[i][j] = __builtin_amdgcn_mfma_f32_16x16x32_bf16(af[i], bq[j], acc[i][j], 0, 0, 0);
  }
  const int crow = wr * 32 + (lane >> 4) * 4;
  const int ccol = wc * 64 + (lane & 15);
#pragma unroll
  for (int i = 0; i < 2; ++i) {
#pragma unroll
    for (int j = 0; j < 4; ++j) {
#pragma unroll
      for (int r = 0; r < 4; ++r) {
        int row = m0 + crow + i * 16 + r;
        int col = n0 + ccol + j * 16;
        float v = acc[i][j][r];
        size_t off = (size_t)row * N + col;
        if (MODE == 2) {
          ((float*)Cout)[off] = v + R[off];
        } else if (MODE == 4) {
          ((float*)Cout)[off] = v;
          ((unsigned short*)Cout2)[off] = f2bf(v);
        } else {  // MODE 5
          float g = v + bias[col];
          float sg = 1.0f / (1.0f + expf(-g));
          ((float*)Cout)[off] = R[off] + R2[off] * sg;
        }
      }
    }
  }
}

// ---------------- MFMA flash attention, 128-query tiles ----------------
__global__ __launch_bounds__(256) void mattn(const unsigned short* __restrict__ qb,
                                             const unsigned short* __restrict__ kb,
                                             const unsigned short* __restrict__ vtb,
                                             unsigned short* __restrict__ out) {
  __shared__ unsigned short Qs[8192];   // 128 x 64
  __shared__ unsigned short Ks[4096];   // 64 x 64
  __shared__ unsigned short Vts[4096];  // 64 d x 64 s
  __shared__ unsigned short Ps[4 * 16 * 72];
  const int qt = gridDim.x - 1 - blockIdx.x;  // heavy tiles dispatch first
  const int bh = blockIdx.y;
  const int b = bh >> 4, h = bh & 15;
  const int t = threadIdx.x, lane = t & 63, w = t >> 6;
  const int l15 = lane & 15, l4 = lane >> 4;
  const unsigned short* qbase = qb + ((size_t)bh * Sc + qt * 128) * 64;
  const unsigned short* kbase = kb + (size_t)bh * Sc * 64;
  const unsigned short* vbase = vtb + (size_t)bh * 64 * Sc;
#pragma unroll
  for (int i = 0; i < 4; ++i) {
    int idx = t + i * 256;
    int r = idx >> 3;
    int cg = (idx & 7) ^ (r & 7);
    gll16(qbase + (size_t)r * 64 + cg * 8, Qs + idx * 8);
  }
  bf16x8 qf[2][2];
  f32x4 oacc[2][4] = {};
  float lrow[2][4] = {};
  unsigned short* pw = Ps + w * 16 * 72;
  const int ktmax = 2 * qt + 1;
  for (int kt = 0; kt <= ktmax; ++kt) {
    __syncthreads();
    {
      int r = t >> 3;
      int cg = (t & 7) ^ (r & 7);
      gll16(kbase + (size_t)(kt * 64 + r) * 64 + cg * 8, Ks + t * 8);
      gll16(kbase + (size_t)(kt * 64 + r + 32) * 64 + cg * 8, Ks + 2048 + t * 8);
      gll16(vbase + (size_t)r * Sc + kt * 64 + cg * 8, Vts + t * 8);
      gll16(vbase + (size_t)(r + 32) * Sc + kt * 64 + cg * 8, Vts + 2048 + t * 8);
    }
    __syncthreads();
    if (kt == 0) {
#pragma unroll
      for (int ch = 0; ch < 2; ++ch) {
        int qrow = ch * 64 + w * 16 + l15;
#pragma unroll
        for (int kc = 0; kc < 2; ++kc)
          qf[ch][kc] = *(const bf16x8*)(Qs + qrow * 64 + (((kc * 4 + l4) ^ (l15 & 7)) * 8));
      }
    }
    const bool actA = (kt <= 2 * qt);
    f32x4 sc[2][4] = {};
#pragma unroll
    for (int kc = 0; kc < 2; ++kc) {
      bf16x8 kf[4];
#pragma unroll
      for (int j = 0; j < 4; ++j)
        kf[j] = *(const bf16x8*)(Ks + (j * 16 + l15) * 64 + (((kc * 4 + l4) ^ (l15 & 7)) * 8));
      if (actA) {
#pragma unroll
        for (int j = 0; j < 4; ++j)
          sc[0][j] = __builtin_amdgcn_mfma_f32_16x16x32_bf16(qf[0][kc], kf[j], sc[0][j], 0, 0, 0);
      }
#pragma unroll
      for (int j = 0; j < 4; ++j)
        sc[1][j] = __builtin_amdgcn_mfma_f32_16x16x32_bf16(qf[1][kc], kf[j], sc[1][j], 0, 0, 0);
    }
    const int rl = w * 16 + l4 * 4;
    if (kt == 2 * qt) {
#pragma unroll
      for (int j = 0; j < 4; ++j)
#pragma unroll
        for (int r = 0; r < 4; ++r)
          if (j * 16 + l15 > rl + r) sc[0][j][r] = -INFINITY;
    }
    if (kt == ktmax) {
#pragma unroll
      for (int j = 0; j < 4; ++j)
#pragma unroll
        for (int r = 0; r < 4; ++r)
          if (j * 16 + l15 > rl + r) sc[1][j][r] = -INFINITY;
    }
    bf16x8 vf[2][4];
#pragma unroll
    for (int kc = 0; kc < 2; ++kc)
#pragma unroll
      for (int j = 0; j < 4; ++j)
        vf[kc][j] = *(const bf16x8*)(Vts + (j * 16 + l15) * 64 + (((kc * 4 + l4) ^ (l15 & 7)) * 8));
#pragma unroll
    for (int ch = 0; ch < 2; ++ch) {
      if (ch == 0 && !actA) continue;
#pragma unroll
      for (int j = 0; j < 4; ++j)
#pragma unroll
        for (int r = 0; r < 4; ++r) {
          float p = exp2f(sc[ch][j][r]);
          lrow[ch][r] += p;
          pw[(l4 * 4 + r) * 72 + j * 16 + l15] = f2bf(p);
        }
      __asm__ __volatile__("s_waitcnt lgkmcnt(0)" ::: "memory");
#pragma unroll
      for (int kc = 0; kc < 2; ++kc) {
        bf16x8 pf = *(const bf16x8*)(pw + l15 * 72 + kc * 32 + l4 * 8);
#pragma unroll
        for (int j = 0; j < 4; ++j)
          oacc[ch][j] = __builtin_amdgcn_mfma_f32_16x16x32_bf16(pf, vf[kc][j], oacc[ch][j], 0, 0, 0);
      }
    }
  }
#pragma unroll
  for (int ch = 0; ch < 2; ++ch) {
#pragma unroll
    for (int r = 0; r < 4; ++r) {
      float s = lrow[ch][r];
      s += __shfl_xor(s, 1);
      s += __shfl_xor(s, 2);
      s += __shfl_xor(s, 4);
      s += __shfl_xor(s, 8);
      float inv = 1.0f / s;
#pragma unroll
      for (int j = 0; j < 4; ++j) {
        int srow = qt * 128 + ch * 64 + w * 16 + l4 * 4 + r;
        out[((size_t)(b * Sc + srow)) * Dc + h * 64 + j * 16 + l15] =
            f2bf(oacc[ch][j][r] * inv);
      }
    }
  }
}

extern "C" void kernel_launch(void* const* d_in, const int* in_sizes, int n_in,
                              void* d_out, int out_size, void* d_ws, size_t ws_size,
                              hipStream_t stream) {
  const float* x        = (const float*)d_in[0];
  const float* qkv_w    = (const float*)d_in[2];
  const float* out_w    = (const float*)d_in[3];
  const float* gate_w   = (const float*)d_in[4];
  const float* gate_b   = (const float*)d_in[5];
  const float* w12      = (const float*)d_in[6];
  const float* w3       = (const float*)d_in[7];
  const float* hh_vs    = (const float*)d_in[8];
  const float* inv_freq = (const float*)d_in[9];
  const float* rope_pos = (const float*)d_in[10];
  char* ws = (char*)d_ws;
  // lifetime-based slots (bytes), peak ~109.07 MB:
  unsigned short* woutb  = (unsigned short*)(ws + 0);          // 2 MiB  [-> outproj]
  unsigned short* wqkvb  = (unsigned short*)(ws + 4194304);    // 6 MiB  [-> qkv GEMM]
  unsigned short* attnb  = (unsigned short*)(ws + 4194304);    // 8 MiB  [mattn -> outproj]
  float*          xmid   = (float*)(ws + 0);                   // 16 MiB [gate GEMM -> end]
  unsigned short* slotB  = (unsigned short*)(ws + 16777216);   // 8 MiB  xn | xn2
  float*          oproj  = (float*)(ws + 25165824);            // 16 MiB [outproj -> gate GEMM]
  unsigned short* w12b   = (unsigned short*)(ws + 25165824);   // 16 MiB [-> w12 GEMM]
  unsigned short* wgateb = (unsigned short*)(ws + 41943040);   // 2 MiB  [-> gate GEMM]
  unsigned short* w3b    = (unsigned short*)(ws + 41943040);   // 8 MiB  [-> w3 GEMM]
  unsigned short* qkvb   = (unsigned short*)(ws + 58720256);   // 24 MiB [qkv GEMM -> rope/vt]
  unsigned short* hbufb  = (unsigned short*)(ws + 58720256);   // 32 MiB [w12 -> w3 GEMM]
  unsigned short* qb     = (unsigned short*)(ws + 83886080);   // 8 MiB  [rope -> mattn]
  unsigned short* oprojb = (unsigned short*)(ws + 83886080);   // 8 MiB  [outproj -> gate GEMM]
  unsigned short* kb     = (unsigned short*)(ws + 92274688);   // 8 MiB
  unsigned short* vtb    = (unsigned short*)(ws + 100663296);  // 8 MiB
  float*          Qb     = (float*)(ws + 109051904);           // 16 KB
  float* outp = (float*)d_out;

  hh_kernel<<<1, 64, 0, stream>>>(hh_vs, Qb);
  wqk_kernel<<<2048, 256, 0, stream>>>(qkv_w, Qb, wqkvb);            // folded q,k weights
  f2b_kernel<<<1024, 256, 0, stream>>>(qkv_w + 2048 * 1024,
                                       wqkvb + 2048 * 1024);          // v weights plain cast
  f2b_kernel<<<1024, 256, 0, stream>>>(out_w, woutb);
  f2b_kernel<<<1024, 256, 0, stream>>>(gate_w, wgateb);
  rmsnorm_bf16_kernel<<<4096, 256, 0, stream>>>(x, slotB);
  mgemm<3><<<dim3(24, 32), 256, 0, stream>>>(slotB, wqkvb, nullptr, qkvb, 4096, 3072, 1024);
  rope_kernel<<<2048, 256, 0, stream>>>(qkvb, rope_pos, inv_freq, qb, kb);
  vt_kernel<<<dim3(32, 32), 256, 0, stream>>>(qkvb, vtb);
  mattn<<<dim3(16, 32), 256, 0, stream>>>(qb, kb, vtb, attnb);
  mgemm64<4><<<dim3(8, 64), 256, 0, stream>>>(attnb, woutb, nullptr, nullptr, nullptr,
                                              oproj, oprojb, 4096, 1024, 1024);
  mgemm64<5><<<dim3(8, 64), 256, 0, stream>>>(oprojb, wgateb, x, oproj, gate_b,
                                              xmid, nullptr, 4096, 1024, 1024);
  f2b_kernel<<<8192, 256, 0, stream>>>(w12, w12b);
  f2b_kernel<<<4096, 256, 0, stream>>>(w3, w3b);
  rmsnorm_bf16_kernel<<<4096, 256, 0, stream>>>(xmid, slotB);
  mgemm<1><<<dim3(32, 32), 256, 0, stream>>>(slotB, w12b, w12b + 4194304, hbufb,
                                             4096, 4096, 1024);
  mgemm64<2><<<dim3(8, 64), 256, 0, stream>>>(hbufb, w3b, xmid, nullptr, nullptr,
                                              outp, nullptr, 4096, 1024, 4096);
}